// Round 1
// baseline (156.544 us; speedup 1.0000x reference)
//
#include <hip/hip_runtime.h>
#include <math.h>

#define TB 8      // batch
#define TT 128    // tokens
#define TD 768    // dim
#define TH 768    // hidden
#define LN_EPS 1e-5f

// ---------------------------------------------------------------------------
// Kernel 1: LayerNorm. One wave per (b,t) row. Writes xn transposed [T][D][B]
// so the GEMM kernels can LDS-stage it with a contiguous copy.
// ---------------------------------------------------------------------------
__global__ __launch_bounds__(256) void ln_kernel(
    const float* __restrict__ x,      // [B][T][D]
    const float* __restrict__ gamma,  // [T][D]
    const float* __restrict__ beta,   // [T][D]
    float* __restrict__ xn) {         // [T][D][B]
  const int w = threadIdx.x >> 6, lane = threadIdx.x & 63;
  const int r = blockIdx.x * 4 + w;   // 0..1023, r = b*T + t
  const int t = r & (TT - 1);
  const int b = r >> 7;
  const float* xr = x + (size_t)r * TD;

  float v[12];
  float s = 0.f, ss = 0.f;
#pragma unroll
  for (int i = 0; i < 3; ++i) {
    float4 f = *(const float4*)(xr + i * 256 + lane * 4);
    v[i * 4 + 0] = f.x; v[i * 4 + 1] = f.y;
    v[i * 4 + 2] = f.z; v[i * 4 + 3] = f.w;
    s += f.x + f.y + f.z + f.w;
    ss += f.x * f.x + f.y * f.y + f.z * f.z + f.w * f.w;
  }
#pragma unroll
  for (int off = 32; off; off >>= 1) {
    s  += __shfl_down(s, off, 64);
    ss += __shfl_down(ss, off, 64);
  }
  s = __shfl(s, 0, 64); ss = __shfl(ss, 0, 64);
  const float mu   = s * (1.f / TD);
  const float var  = ss * (1.f / TD) - mu * mu;
  const float rstd = rsqrtf(var + LN_EPS);

#pragma unroll
  for (int i = 0; i < 3; ++i) {
    const int d = i * 256 + lane * 4;
    float4 g  = *(const float4*)(gamma + (size_t)t * TD + d);
    float4 be = *(const float4*)(beta  + (size_t)t * TD + d);
    float* o = xn + ((size_t)t * TD + d) * TB + b;
    o[0 * TB] = (v[i * 4 + 0] - mu) * rstd * g.x + be.x;
    o[1 * TB] = (v[i * 4 + 1] - mu) * rstd * g.y + be.y;
    o[2 * TB] = (v[i * 4 + 2] - mu) * rstd * g.z + be.z;
    o[3 * TB] = (v[i * 4 + 3] - mu) * rstd * g.w + be.w;
  }
}

// ---------------------------------------------------------------------------
// Kernel 2: h = gelu(xn @ W1 + b1), per token. Block = (t, 128-col slice),
// 2 waves split K=768 into 2x384. Lane owns 2 cols (float2 weight loads).
// ---------------------------------------------------------------------------
__global__ __launch_bounds__(128) void ff1_kernel(
    const float* __restrict__ xn,   // [T][D][B]
    const float* __restrict__ W1,   // [T][D][H]
    const float* __restrict__ b1,   // [T][H]
    float* __restrict__ hbuf) {     // [T][H][B]
  __shared__ float st[TD * TB];     // 24 KB staged activations
  __shared__ float red[64 * 16];    // 4 KB cross-wave reduction
  const int tid = threadIdx.x;
  const int w = tid >> 6, lane = tid & 63;
  const int t = blockIdx.x / 6, slice = blockIdx.x % 6;
  const int d0 = w * (TD / 2);

  {  // each wave stages its own K-half: 384*8 floats contiguous
    const float4* src = (const float4*)(xn + ((size_t)t * TD + d0) * TB);
    float4* dst = (float4*)(st + d0 * TB);
#pragma unroll
    for (int i = 0; i < 12; ++i) dst[lane + i * 64] = src[lane + i * 64];
  }

  const int c = slice * 128 + lane * 2;
  const float* wp = W1 + ((size_t)t * TD + d0) * TH + c;
  const float* xbase = st + d0 * TB;
  float acc[8][2];
#pragma unroll
  for (int b = 0; b < 8; ++b) acc[b][0] = acc[b][1] = 0.f;

#pragma unroll 4
  for (int d = 0; d < TD / 2; ++d) {
    const float2 wv = *(const float2*)wp;
    wp += TH;
    const float4 xa = *(const float4*)(xbase + d * 8);
    const float4 xb = *(const float4*)(xbase + d * 8 + 4);
    const float xv[8] = {xa.x, xa.y, xa.z, xa.w, xb.x, xb.y, xb.z, xb.w};
#pragma unroll
    for (int b = 0; b < 8; ++b) {
      acc[b][0] = fmaf(xv[b], wv.x, acc[b][0]);
      acc[b][1] = fmaf(xv[b], wv.y, acc[b][1]);
    }
  }

  if (w == 1) {
#pragma unroll
    for (int b = 0; b < 8; ++b) {
      red[lane * 16 + 2 * b]     = acc[b][0];
      red[lane * 16 + 2 * b + 1] = acc[b][1];
    }
  }
  __syncthreads();
  if (w == 0) {
    const float2 bias = *(const float2*)(b1 + (size_t)t * TH + c);
    float r0[8], r1[8];
#pragma unroll
    for (int b = 0; b < 8; ++b) {
      float v0 = acc[b][0] + red[lane * 16 + 2 * b]     + bias.x;
      float v1 = acc[b][1] + red[lane * 16 + 2 * b + 1] + bias.y;
      r0[b] = 0.5f * v0 * (1.f + erff(v0 * 0.7071067811865476f));
      r1[b] = 0.5f * v1 * (1.f + erff(v1 * 0.7071067811865476f));
    }
    float4* hp = (float4*)(hbuf + ((size_t)t * TH + c) * TB);
    hp[0] = make_float4(r0[0], r0[1], r0[2], r0[3]);
    hp[1] = make_float4(r0[4], r0[5], r0[6], r0[7]);
    hp[2] = make_float4(r1[0], r1[1], r1[2], r1[3]);
    hp[3] = make_float4(r1[4], r1[5], r1[6], r1[7]);
  }
}

// ---------------------------------------------------------------------------
// Kernel 3: out = h @ W2 + b2 + x (residual). Same structure as ff1.
// ---------------------------------------------------------------------------
__global__ __launch_bounds__(128) void ff2_kernel(
    const float* __restrict__ hbuf, // [T][H][B]
    const float* __restrict__ W2,   // [T][H][D]
    const float* __restrict__ b2,   // [T][D]
    const float* __restrict__ x,    // [B][T][D]
    float* __restrict__ out) {      // [B][T][D]
  __shared__ float st[TH * TB];
  __shared__ float red[64 * 16];
  const int tid = threadIdx.x;
  const int w = tid >> 6, lane = tid & 63;
  const int t = blockIdx.x / 6, slice = blockIdx.x % 6;
  const int h0 = w * (TH / 2);

  {
    const float4* src = (const float4*)(hbuf + ((size_t)t * TH + h0) * TB);
    float4* dst = (float4*)(st + h0 * TB);
#pragma unroll
    for (int i = 0; i < 12; ++i) dst[lane + i * 64] = src[lane + i * 64];
  }

  const int c = slice * 128 + lane * 2;
  const float* wp = W2 + ((size_t)t * TH + h0) * TD + c;
  const float* hbase = st + h0 * TB;
  float acc[8][2];
#pragma unroll
  for (int b = 0; b < 8; ++b) acc[b][0] = acc[b][1] = 0.f;

#pragma unroll 4
  for (int hh = 0; hh < TH / 2; ++hh) {
    const float2 wv = *(const float2*)wp;
    wp += TD;
    const float4 ha = *(const float4*)(hbase + hh * 8);
    const float4 hb = *(const float4*)(hbase + hh * 8 + 4);
    const float hv[8] = {ha.x, ha.y, ha.z, ha.w, hb.x, hb.y, hb.z, hb.w};
#pragma unroll
    for (int b = 0; b < 8; ++b) {
      acc[b][0] = fmaf(hv[b], wv.x, acc[b][0]);
      acc[b][1] = fmaf(hv[b], wv.y, acc[b][1]);
    }
  }

  if (w == 1) {
#pragma unroll
    for (int b = 0; b < 8; ++b) {
      red[lane * 16 + 2 * b]     = acc[b][0];
      red[lane * 16 + 2 * b + 1] = acc[b][1];
    }
  }
  __syncthreads();
  if (w == 0) {
    const float2 bias = *(const float2*)(b2 + (size_t)t * TD + c);
#pragma unroll
    for (int b = 0; b < 8; ++b) {
      const float* xp = x + ((size_t)b * TT + t) * TD + c;
      const float2 xv = *(const float2*)xp;
      float2 o;
      o.x = acc[b][0] + red[lane * 16 + 2 * b]     + bias.x + xv.x;
      o.y = acc[b][1] + red[lane * 16 + 2 * b + 1] + bias.y + xv.y;
      *(float2*)(out + ((size_t)b * TT + t) * TD + c) = o;
    }
  }
}

extern "C" void kernel_launch(void* const* d_in, const int* in_sizes, int n_in,
                              void* d_out, int out_size, void* d_ws, size_t ws_size,
                              hipStream_t stream) {
  const float* x     = (const float*)d_in[0];
  const float* gamma = (const float*)d_in[1];
  const float* beta  = (const float*)d_in[2];
  const float* W1    = (const float*)d_in[3];
  const float* b1    = (const float*)d_in[4];
  const float* W2    = (const float*)d_in[5];
  const float* b2    = (const float*)d_in[6];
  float* out = (float*)d_out;

  float* xn   = (float*)d_ws;                       // [T][D][B] = 3 MB
  float* hbuf = xn + (size_t)TT * TD * TB;          // [T][H][B] = 3 MB

  ln_kernel<<<256, 256, 0, stream>>>(x, gamma, beta, xn);
  ff1_kernel<<<TT * 6, 128, 0, stream>>>(xn, W1, b1, hbuf);
  ff2_kernel<<<TT * 6, 128, 0, stream>>>(hbuf, W2, b2, x, out);
}

// Round 2
// 121.293 us; speedup vs baseline: 1.2906x; 1.2906x over previous
//
#include <hip/hip_runtime.h>
#include <math.h>

#define TB 8      // batch
#define TT 128    // tokens
#define TD 768    // dim
#define TH 768    // hidden
#define LN_EPS 1e-5f

// ---------------------------------------------------------------------------
// Kernel 1: LayerNorm. One wave per (b,t) row. Writes xn transposed [T][D][B]
// so the GEMM kernels can LDS-stage it with a contiguous copy.
// ---------------------------------------------------------------------------
__global__ __launch_bounds__(256) void ln_kernel(
    const float* __restrict__ x,      // [B][T][D]
    const float* __restrict__ gamma,  // [T][D]
    const float* __restrict__ beta,   // [T][D]
    float* __restrict__ xn) {         // [T][D][B]
  const int w = threadIdx.x >> 6, lane = threadIdx.x & 63;
  const int r = blockIdx.x * 4 + w;   // 0..1023, r = b*T + t
  const int t = r & (TT - 1);
  const int b = r >> 7;
  const float* xr = x + (size_t)r * TD;

  float v[12];
  float s = 0.f, ss = 0.f;
#pragma unroll
  for (int i = 0; i < 3; ++i) {
    float4 f = *(const float4*)(xr + i * 256 + lane * 4);
    v[i * 4 + 0] = f.x; v[i * 4 + 1] = f.y;
    v[i * 4 + 2] = f.z; v[i * 4 + 3] = f.w;
    s += f.x + f.y + f.z + f.w;
    ss += f.x * f.x + f.y * f.y + f.z * f.z + f.w * f.w;
  }
#pragma unroll
  for (int off = 32; off; off >>= 1) {
    s  += __shfl_down(s, off, 64);
    ss += __shfl_down(ss, off, 64);
  }
  s = __shfl(s, 0, 64); ss = __shfl(ss, 0, 64);
  const float mu   = s * (1.f / TD);
  const float var  = ss * (1.f / TD) - mu * mu;
  const float rstd = rsqrtf(var + LN_EPS);

#pragma unroll
  for (int i = 0; i < 3; ++i) {
    const int d = i * 256 + lane * 4;
    float4 g  = *(const float4*)(gamma + (size_t)t * TD + d);
    float4 be = *(const float4*)(beta  + (size_t)t * TD + d);
    float* o = xn + ((size_t)t * TD + d) * TB + b;
    o[0 * TB] = (v[i * 4 + 0] - mu) * rstd * g.x + be.x;
    o[1 * TB] = (v[i * 4 + 1] - mu) * rstd * g.y + be.y;
    o[2 * TB] = (v[i * 4 + 2] - mu) * rstd * g.z + be.z;
    o[3 * TB] = (v[i * 4 + 3] - mu) * rstd * g.w + be.w;
  }
}

// ---------------------------------------------------------------------------
// FF GEMM structure (both kernels): block = (token t, 128-col slice).
// 256 threads = 4 waves; each wave's two 32-lane halves take 96-row K-chunks
// (8-way K split). Lane owns 4 cols via float4 weight loads (16 B/lane).
// Partials: shfl_xor(32) -> LDS red[4][8][128] (float4, conflict-free) ->
// parallel 256-thread epilogue.
// ---------------------------------------------------------------------------
__global__ __launch_bounds__(256) void ff1_kernel(
    const float* __restrict__ xn,   // [T][D][B]
    const float* __restrict__ W1,   // [T][D][H]
    const float* __restrict__ b1,   // [T][H]
    float* __restrict__ hbuf) {     // [T][H][B]
  __shared__ float st[TD * TB];       // 24 KB staged activations
  __shared__ float red[4][8][128];    // 16 KB partial sums
  const int tid = threadIdx.x;
  const int w = tid >> 6, lane = tid & 63;
  const int t = blockIdx.x / 6, slice = blockIdx.x % 6;

  {  // cooperative stage of xn[t][*][*]: 1536 float4s over 256 threads
    const float4* src = (const float4*)(xn + (size_t)t * TD * TB);
    float4* dst = (float4*)st;
#pragma unroll
    for (int i = 0; i < 6; ++i) dst[tid + i * 256] = src[tid + i * 256];
  }
  __syncthreads();

  const int half = lane >> 5;
  const int cg = (lane & 31) * 4;          // col within 128-col slice
  const int c = slice * 128 + cg;
  const int r0 = w * 192 + half * 96;      // this half-wave's K-chunk
  const float* wp = W1 + ((size_t)t * TD + r0) * TH + c;
  const float* xb = st + r0 * TB;

  float acc[8][4];
#pragma unroll
  for (int b = 0; b < 8; ++b)
#pragma unroll
    for (int j = 0; j < 4; ++j) acc[b][j] = 0.f;

#pragma unroll 4
  for (int d = 0; d < 96; ++d) {
    const float4 wv = *(const float4*)wp;
    wp += TH;
    const float4 xa = *(const float4*)(xb + d * 8);
    const float4 xc = *(const float4*)(xb + d * 8 + 4);
    const float xv[8] = {xa.x, xa.y, xa.z, xa.w, xc.x, xc.y, xc.z, xc.w};
#pragma unroll
    for (int b = 0; b < 8; ++b) {
      acc[b][0] = fmaf(xv[b], wv.x, acc[b][0]);
      acc[b][1] = fmaf(xv[b], wv.y, acc[b][1]);
      acc[b][2] = fmaf(xv[b], wv.z, acc[b][2]);
      acc[b][3] = fmaf(xv[b], wv.w, acc[b][3]);
    }
  }

#pragma unroll
  for (int b = 0; b < 8; ++b)
#pragma unroll
    for (int j = 0; j < 4; ++j)
      acc[b][j] += __shfl_xor(acc[b][j], 32, 64);

  if (lane < 32) {
#pragma unroll
    for (int b = 0; b < 8; ++b)
      *(float4*)&red[w][b][cg] =
          make_float4(acc[b][0], acc[b][1], acc[b][2], acc[b][3]);
  }
  __syncthreads();

  {  // epilogue: thread -> (col, batch-quad)
    const int col = tid >> 1;
    const int bq = (tid & 1) * 4;
    const int cc = slice * 128 + col;
    const float bias = b1[(size_t)t * TH + cc];
    float4 o;
    float* po = (float*)&o;
#pragma unroll
    for (int i = 0; i < 4; ++i) {
      float v = red[0][bq + i][col] + red[1][bq + i][col] +
                red[2][bq + i][col] + red[3][bq + i][col] + bias;
      po[i] = 0.5f * v * (1.f + erff(v * 0.7071067811865476f));
    }
    *(float4*)(hbuf + ((size_t)t * TH + cc) * TB + bq) = o;
  }
}

__global__ __launch_bounds__(256) void ff2_kernel(
    const float* __restrict__ hbuf, // [T][H][B]
    const float* __restrict__ W2,   // [T][H][D]
    const float* __restrict__ b2,   // [T][D]
    const float* __restrict__ x,    // [B][T][D]
    float* __restrict__ out) {      // [B][T][D]
  __shared__ float st[TH * TB];
  __shared__ float red[4][8][128];
  const int tid = threadIdx.x;
  const int w = tid >> 6, lane = tid & 63;
  const int t = blockIdx.x / 6, slice = blockIdx.x % 6;

  {
    const float4* src = (const float4*)(hbuf + (size_t)t * TH * TB);
    float4* dst = (float4*)st;
#pragma unroll
    for (int i = 0; i < 6; ++i) dst[tid + i * 256] = src[tid + i * 256];
  }
  __syncthreads();

  const int half = lane >> 5;
  const int cg = (lane & 31) * 4;
  const int c = slice * 128 + cg;
  const int r0 = w * 192 + half * 96;
  const float* wp = W2 + ((size_t)t * TH + r0) * TD + c;
  const float* hb = st + r0 * TB;

  float acc[8][4];
#pragma unroll
  for (int b = 0; b < 8; ++b)
#pragma unroll
    for (int j = 0; j < 4; ++j) acc[b][j] = 0.f;

#pragma unroll 4
  for (int d = 0; d < 96; ++d) {
    const float4 wv = *(const float4*)wp;
    wp += TD;
    const float4 ha = *(const float4*)(hb + d * 8);
    const float4 hc = *(const float4*)(hb + d * 8 + 4);
    const float hv[8] = {ha.x, ha.y, ha.z, ha.w, hc.x, hc.y, hc.z, hc.w};
#pragma unroll
    for (int b = 0; b < 8; ++b) {
      acc[b][0] = fmaf(hv[b], wv.x, acc[b][0]);
      acc[b][1] = fmaf(hv[b], wv.y, acc[b][1]);
      acc[b][2] = fmaf(hv[b], wv.z, acc[b][2]);
      acc[b][3] = fmaf(hv[b], wv.w, acc[b][3]);
    }
  }

#pragma unroll
  for (int b = 0; b < 8; ++b)
#pragma unroll
    for (int j = 0; j < 4; ++j)
      acc[b][j] += __shfl_xor(acc[b][j], 32, 64);

  if (lane < 32) {
#pragma unroll
    for (int b = 0; b < 8; ++b)
      *(float4*)&red[w][b][cg] =
          make_float4(acc[b][0], acc[b][1], acc[b][2], acc[b][3]);
  }
  __syncthreads();

  {
    const int col = tid >> 1;
    const int bq = (tid & 1) * 4;
    const int cc = slice * 128 + col;
    const float bias = b2[(size_t)t * TD + cc];
#pragma unroll
    for (int i = 0; i < 4; ++i) {
      const size_t off = ((size_t)(bq + i) * TT + t) * TD + cc;
      float v = red[0][bq + i][col] + red[1][bq + i][col] +
                red[2][bq + i][col] + red[3][bq + i][col] + bias + x[off];
      out[off] = v;
    }
  }
}

extern "C" void kernel_launch(void* const* d_in, const int* in_sizes, int n_in,
                              void* d_out, int out_size, void* d_ws, size_t ws_size,
                              hipStream_t stream) {
  const float* x     = (const float*)d_in[0];
  const float* gamma = (const float*)d_in[1];
  const float* beta  = (const float*)d_in[2];
  const float* W1    = (const float*)d_in[3];
  const float* b1    = (const float*)d_in[4];
  const float* W2    = (const float*)d_in[5];
  const float* b2    = (const float*)d_in[6];
  float* out = (float*)d_out;

  float* xn   = (float*)d_ws;                       // [T][D][B] = 3 MB
  float* hbuf = xn + (size_t)TT * TD * TB;          // [T][H][B] = 3 MB

  ln_kernel<<<256, 256, 0, stream>>>(x, gamma, beta, xn);
  ff1_kernel<<<TT * 6, 256, 0, stream>>>(xn, W1, b1, hbuf);
  ff2_kernel<<<TT * 6, 256, 0, stream>>>(hbuf, W2, b2, x, out);
}

// Round 3
// 115.582 us; speedup vs baseline: 1.3544x; 1.0494x over previous
//
#include <hip/hip_runtime.h>
#include <math.h>

#define TB 8      // batch
#define TT 128    // tokens
#define TD 768    // dim
#define TH 768    // hidden
#define LN_EPS 1e-5f

// ---------------------------------------------------------------------------
// FF1 with fused LayerNorm. Block = (token t, 128-col slice of H), 256 thr.
// LN: wave w half h handles batch row b = 2w+h (32 lanes over D=768),
// result staged to st[b][d] in LDS (lane-contiguous float4 writes).
// GEMM: half-wave owns a 96-row K-chunk, lane owns 4 cols (float4 weight
// loads, 16 B/lane, 8 in flight). x reads from LDS are per-half broadcasts.
// ---------------------------------------------------------------------------
__global__ __launch_bounds__(256) void ff1_kernel(
    const float* __restrict__ x,      // [B][T][D]
    const float* __restrict__ gamma,  // [T][D]
    const float* __restrict__ beta,   // [T][D]
    const float* __restrict__ W1,     // [T][D][H]
    const float* __restrict__ b1,     // [T][H]
    float* __restrict__ hbuf) {       // [T][B][H]
  __shared__ float st[TB][TD];        // 24 KB normalized activations
  __shared__ float red[4][8][128];    // 16 KB partial sums
  const int tid = threadIdx.x;
  const int w = tid >> 6, lane = tid & 63;
  const int half = lane >> 5, l32 = lane & 31;
  const int t = blockIdx.x / 6, slice = blockIdx.x % 6;

  {  // ---- fused LN for batch row b = 2w + half
    const int b = w * 2 + half;
    const float* xr = x + ((size_t)b * TT + t) * TD;
    float4 v[6];
    float s = 0.f, ss = 0.f;
#pragma unroll
    for (int i = 0; i < 6; ++i) {
      v[i] = *(const float4*)(xr + i * 128 + l32 * 4);
      s += v[i].x + v[i].y + v[i].z + v[i].w;
      ss += v[i].x * v[i].x + v[i].y * v[i].y + v[i].z * v[i].z + v[i].w * v[i].w;
    }
#pragma unroll
    for (int off = 16; off; off >>= 1) {  // stays within the 32-lane half
      s  += __shfl_xor(s, off, 64);
      ss += __shfl_xor(ss, off, 64);
    }
    const float mu   = s * (1.f / TD);
    const float var  = ss * (1.f / TD) - mu * mu;
    const float rstd = rsqrtf(var + LN_EPS);
#pragma unroll
    for (int i = 0; i < 6; ++i) {
      const int d = i * 128 + l32 * 4;
      const float4 g  = *(const float4*)(gamma + (size_t)t * TD + d);
      const float4 be = *(const float4*)(beta  + (size_t)t * TD + d);
      float4 o;
      o.x = (v[i].x - mu) * rstd * g.x + be.x;
      o.y = (v[i].y - mu) * rstd * g.y + be.y;
      o.z = (v[i].z - mu) * rstd * g.z + be.z;
      o.w = (v[i].w - mu) * rstd * g.w + be.w;
      *(float4*)&st[b][d] = o;
    }
  }
  __syncthreads();

  const int cg = l32 * 4;
  const int c = slice * 128 + cg;
  const int r0 = w * 192 + half * 96;
  const float* wp = W1 + ((size_t)t * TD + r0) * TH + c;

  float acc[8][4];
#pragma unroll
  for (int b = 0; b < 8; ++b)
#pragma unroll
    for (int j = 0; j < 4; ++j) acc[b][j] = 0.f;

#pragma unroll 2
  for (int dd = 0; dd < 96; dd += 4) {
    float4 wv[4];
#pragma unroll
    for (int k = 0; k < 4; ++k) wv[k] = *(const float4*)(wp + k * TH);
    wp += 4 * TH;
    float4 xq[8];
#pragma unroll
    for (int b = 0; b < 8; ++b) xq[b] = *(const float4*)&st[b][r0 + dd];
#pragma unroll
    for (int k = 0; k < 4; ++k)
#pragma unroll
      for (int b = 0; b < 8; ++b) {
        const float xv = ((const float*)&xq[b])[k];
        acc[b][0] = fmaf(xv, wv[k].x, acc[b][0]);
        acc[b][1] = fmaf(xv, wv[k].y, acc[b][1]);
        acc[b][2] = fmaf(xv, wv[k].z, acc[b][2]);
        acc[b][3] = fmaf(xv, wv[k].w, acc[b][3]);
      }
  }

#pragma unroll
  for (int b = 0; b < 8; ++b)
#pragma unroll
    for (int j = 0; j < 4; ++j)
      acc[b][j] += __shfl_xor(acc[b][j], 32, 64);

  if (lane < 32) {
#pragma unroll
    for (int b = 0; b < 8; ++b)
      *(float4*)&red[w][b][cg] =
          make_float4(acc[b][0], acc[b][1], acc[b][2], acc[b][3]);
  }
  __syncthreads();

  {  // epilogue: thread -> (batch row b, 4-col group)
    const int b = tid >> 5;
    const int colq = (tid & 31) * 4;
    const int cc = slice * 128 + colq;
    const float4 bias = *(const float4*)(b1 + (size_t)t * TH + cc);
    float4 o;
    float* po = (float*)&o;
    const float* pb = (const float*)&bias;
#pragma unroll
    for (int k = 0; k < 4; ++k) {
      float vv = red[0][b][colq + k] + red[1][b][colq + k] +
                 red[2][b][colq + k] + red[3][b][colq + k] + pb[k];
      po[k] = 0.5f * vv * (1.f + erff(vv * 0.7071067811865476f));
    }
    *(float4*)(hbuf + ((size_t)t * TB + b) * TH + cc) = o;
  }
}

// ---------------------------------------------------------------------------
// FF2: out = h @ W2 + b2 + x. Same GEMM structure; h staged from [T][B][H]
// with a contiguous copy; epilogue/residual are 512B-contiguous per b.
// ---------------------------------------------------------------------------
__global__ __launch_bounds__(256) void ff2_kernel(
    const float* __restrict__ hbuf, // [T][B][H]
    const float* __restrict__ W2,   // [T][H][D]
    const float* __restrict__ b2,   // [T][D]
    const float* __restrict__ x,    // [B][T][D]
    float* __restrict__ out) {      // [B][T][D]
  __shared__ float st[TB][TH];
  __shared__ float red[4][8][128];
  const int tid = threadIdx.x;
  const int w = tid >> 6, lane = tid & 63;
  const int half = lane >> 5, l32 = lane & 31;
  const int t = blockIdx.x / 6, slice = blockIdx.x % 6;

  {  // contiguous stage: hbuf[t] is [8][768] = exactly st's layout
    const float4* src = (const float4*)(hbuf + (size_t)t * TB * TH);
    float4* dst = (float4*)&st[0][0];
#pragma unroll
    for (int i = 0; i < 6; ++i) dst[tid + i * 256] = src[tid + i * 256];
  }
  __syncthreads();

  const int cg = l32 * 4;
  const int c = slice * 128 + cg;
  const int r0 = w * 192 + half * 96;
  const float* wp = W2 + ((size_t)t * TH + r0) * TD + c;

  float acc[8][4];
#pragma unroll
  for (int b = 0; b < 8; ++b)
#pragma unroll
    for (int j = 0; j < 4; ++j) acc[b][j] = 0.f;

#pragma unroll 2
  for (int dd = 0; dd < 96; dd += 4) {
    float4 wv[4];
#pragma unroll
    for (int k = 0; k < 4; ++k) wv[k] = *(const float4*)(wp + k * TD);
    wp += 4 * TD;
    float4 hq[8];
#pragma unroll
    for (int b = 0; b < 8; ++b) hq[b] = *(const float4*)&st[b][r0 + dd];
#pragma unroll
    for (int k = 0; k < 4; ++k)
#pragma unroll
      for (int b = 0; b < 8; ++b) {
        const float hv = ((const float*)&hq[b])[k];
        acc[b][0] = fmaf(hv, wv[k].x, acc[b][0]);
        acc[b][1] = fmaf(hv, wv[k].y, acc[b][1]);
        acc[b][2] = fmaf(hv, wv[k].z, acc[b][2]);
        acc[b][3] = fmaf(hv, wv[k].w, acc[b][3]);
      }
  }

#pragma unroll
  for (int b = 0; b < 8; ++b)
#pragma unroll
    for (int j = 0; j < 4; ++j)
      acc[b][j] += __shfl_xor(acc[b][j], 32, 64);

  if (lane < 32) {
#pragma unroll
    for (int b = 0; b < 8; ++b)
      *(float4*)&red[w][b][cg] =
          make_float4(acc[b][0], acc[b][1], acc[b][2], acc[b][3]);
  }
  __syncthreads();

  {  // epilogue: thread -> (batch row b, 4-col group); coalesced out/x
    const int b = tid >> 5;
    const int colq = (tid & 31) * 4;
    const int cc = slice * 128 + colq;
    const size_t off = ((size_t)b * TT + t) * TD + cc;
    const float4 bias = *(const float4*)(b2 + (size_t)t * TD + cc);
    const float4 xres = *(const float4*)(x + off);
    float4 o;
    float* po = (float*)&o;
    const float* pb = (const float*)&bias;
    const float* px = (const float*)&xres;
#pragma unroll
    for (int k = 0; k < 4; ++k)
      po[k] = red[0][b][colq + k] + red[1][b][colq + k] +
              red[2][b][colq + k] + red[3][b][colq + k] + pb[k] + px[k];
    *(float4*)(out + off) = o;
  }
}

extern "C" void kernel_launch(void* const* d_in, const int* in_sizes, int n_in,
                              void* d_out, int out_size, void* d_ws, size_t ws_size,
                              hipStream_t stream) {
  const float* x     = (const float*)d_in[0];
  const float* gamma = (const float*)d_in[1];
  const float* beta  = (const float*)d_in[2];
  const float* W1    = (const float*)d_in[3];
  const float* b1    = (const float*)d_in[4];
  const float* W2    = (const float*)d_in[5];
  const float* b2    = (const float*)d_in[6];
  float* out = (float*)d_out;

  float* hbuf = (float*)d_ws;   // [T][B][H] = 3 MB

  ff1_kernel<<<TT * 6, 256, 0, stream>>>(x, gamma, beta, W1, b1, hbuf);
  ff2_kernel<<<TT * 6, 256, 0, stream>>>(hbuf, W2, b2, x, out);
}